// Round 3
// baseline (240.796 us; speedup 1.0000x reference)
//
#include <hip/hip_runtime.h>
#include <hip/hip_bf16.h>
#include <cstdint>
#include <cstddef>

#define HID 512
#define T_SZ 4096

typedef __bf16 bf16x8 __attribute__((ext_vector_type(8)));
typedef float f32x4 __attribute__((ext_vector_type(4)));

__device__ __forceinline__ unsigned short f2bf_rne(float f) {
    unsigned int u = __float_as_uint(f);
    unsigned int r = (u + 0x7FFFu + ((u >> 16) & 1u)) >> 16;
    return (unsigned short)r;
}

__device__ __forceinline__ bf16x8 pack8(float4 x0, float4 x1) {
    bf16x8 r;
    r[0] = (__bf16)x0.x; r[1] = (__bf16)x0.y; r[2] = (__bf16)x0.z; r[3] = (__bf16)x0.w;
    r[4] = (__bf16)x1.x; r[5] = (__bf16)x1.y; r[6] = (__bf16)x1.z; r[7] = (__bf16)x1.w;
    return r;
}

__device__ __forceinline__ float fast_tanh(float x) {
    float e = __expf(2.0f * x);
    return 1.0f - 2.0f / (e + 1.0f);
}

// ---------------- kernel 1: s[b][n] = dot(dec[b,:], Ws[n,:]) ----------------
__global__ void k_s(const float* __restrict__ dec, const float* __restrict__ Ws,
                    float* __restrict__ s) {
    int idx = blockIdx.x * 256 + threadIdx.x;   // 16384 = 32*512
    int b = idx >> 9, n = idx & 511;
    const float4* dp = reinterpret_cast<const float4*>(dec + (size_t)b * HID);
    const float4* wp = reinterpret_cast<const float4*>(Ws + (size_t)n * HID);
    float acc = 0.f;
#pragma unroll 8
    for (int i = 0; i < HID / 4; ++i) {
        float4 d = dp[i], w = wp[i];
        acc += d.x * w.x + d.y * w.y + d.z * w.z + d.w * w.w;
    }
    s[idx] = acc;
}

// ------------- kernel 2: pack W_h -> bf16 fragments (kk-major) --------------
// Chunk index = kk*2048 + n4*64 + (g*16 + c); chunk (uint4) holds
// W[n4*16 + c][kk*32 + g*8 + j], j=0..7 as bf16.  A wave reading chunk
// [kk*2048 + n4*64 + lane] gets the MFMA B-fragment, 1KB contiguous.
__global__ void k_pack(const float* __restrict__ Wh, uint4* __restrict__ Wb) {
    int idx = blockIdx.x * 256 + threadIdx.x;   // 32768, 8 elems each
    int n = idx >> 6;
    int k0 = (idx & 63) * 8;
    const float4* p = reinterpret_cast<const float4*>(Wh + (size_t)n * HID + k0);
    float4 x0 = p[0], x1 = p[1];
    uint4 w;
    w.x = f2bf_rne(x0.x) | ((unsigned)f2bf_rne(x0.y) << 16);
    w.y = f2bf_rne(x0.z) | ((unsigned)f2bf_rne(x0.w) << 16);
    w.z = f2bf_rne(x1.x) | ((unsigned)f2bf_rne(x1.y) << 16);
    w.w = f2bf_rne(x1.z) | ((unsigned)f2bf_rne(x1.w) << 16);
    int n4 = n >> 4, c = n & 15, kk = k0 >> 5, g = (k0 >> 3) & 3;
    Wb[(size_t)kk * 2048 + n4 * 64 + g * 16 + c] = w;
}

// ------------- kernel 3: fused h = enc@Wh^T ; e = sum_n tanh(h+s).v ---------
// BM=64, BN=512 (full N), 4 waves each 64x128 (two 64x64 register halves).
// Whole A tile (64x512 bf16 = 64KB) staged ONCE in LDS, fragment-ordered
// (all ds accesses linear-in-lane -> zero bank conflicts). ONE barrier.
// B streamed from L2-resident packed Wb directly to registers, 1 step ahead.
__global__ void __launch_bounds__(256, 2) k_gemm_e(
    const float* __restrict__ enc, const uint4* __restrict__ Wb,
    const float* __restrict__ s, const float* __restrict__ v,
    float* __restrict__ e_out) {
    __shared__ __align__(16) unsigned char As[65536];  // [kk][chunk=mi*64+g4*16+c] 16B
    __shared__ float red[4][64];

    const int tid = threadIdx.x;
    const size_t row0 = (size_t)blockIdx.x * 64;
    const int b = (int)(row0 >> 12);
    const int lane = tid & 63, wid = tid >> 6;
    const int c = lane & 15, g4 = lane >> 4;

    // epilogue constants (L2-resident, tiny)
    float sv_s[8], sv_v[8];
#pragma unroll
    for (int i = 0; i < 8; ++i) {
        int n = wid * 128 + i * 16 + c;
        sv_s[i] = s[b * HID + n];
        sv_v[i] = v[n];
    }

    // ---- stage full A tile: thread t owns chunk t of every kk ----
    // chunk t: row = (t>>6)*16 + (t&15), k8 = (t>>4)&3
    {
        const int row = ((tid >> 6) << 4) + (tid & 15);
        const int k8 = (tid >> 4) & 3;
        const float* Ag = enc + (row0 + row) * HID + k8 * 8;
        const int lbase = tid * 16;
#pragma unroll
        for (int kk = 0; kk < 16; ++kk) {
            float4 x0 = *reinterpret_cast<const float4*>(Ag + kk * 32);
            float4 x1 = *reinterpret_cast<const float4*>(Ag + kk * 32 + 4);
            *reinterpret_cast<bf16x8*>(&As[lbase + kk * 4096]) = pack8(x0, x1);
        }
    }
    __syncthreads();

    const uint4* Bg = Wb + wid * 512 + lane;   // + kk*2048 + (h*4+ni)*64

    float e_part[4][4] = {};   // [mi][r]

#pragma unroll
    for (int h = 0; h < 2; ++h) {
        f32x4 acc[4][4] = {};          // [mi][ni]
        bf16x8 aR[2][4];
        uint4  bR[2][4];
#pragma unroll
        for (int mi = 0; mi < 4; ++mi)
            aR[0][mi] = *reinterpret_cast<const bf16x8*>(&As[(mi * 64 + lane) * 16]);
#pragma unroll
        for (int ni = 0; ni < 4; ++ni)
            bR[0][ni] = Bg[(h * 4 + ni) * 64];

#pragma unroll
        for (int kk = 0; kk < 16; ++kk) {
            const int cur = kk & 1, nxt = cur ^ 1;
            if (kk < 15) {
#pragma unroll
                for (int mi = 0; mi < 4; ++mi)
                    aR[nxt][mi] = *reinterpret_cast<const bf16x8*>(
                        &As[(kk + 1) * 4096 + (mi * 64 + lane) * 16]);
#pragma unroll
                for (int ni = 0; ni < 4; ++ni)
                    bR[nxt][ni] = Bg[(size_t)(kk + 1) * 2048 + (h * 4 + ni) * 64];
            }
#pragma unroll
            for (int mi = 0; mi < 4; ++mi)
#pragma unroll
                for (int ni = 0; ni < 4; ++ni)
                    acc[mi][ni] = __builtin_amdgcn_mfma_f32_16x16x32_bf16(
                        aR[cur][mi], *reinterpret_cast<bf16x8*>(&bR[cur][ni]),
                        acc[mi][ni], 0, 0, 0);
        }

        // epilogue accumulate: e_part += tanh(h + s[n]) * v[n]
#pragma unroll
        for (int ni = 0; ni < 4; ++ni) {
            float sn = sv_s[h * 4 + ni], vn = sv_v[h * 4 + ni];
#pragma unroll
            for (int mi = 0; mi < 4; ++mi)
#pragma unroll
                for (int r = 0; r < 4; ++r)
                    e_part[mi][r] += fast_tanh(acc[mi][ni][r] + sn) * vn;
        }
    }

    // reduce across the 16 n-residue lanes (bits 0..3)
#pragma unroll
    for (int m = 1; m <= 8; m <<= 1)
#pragma unroll
        for (int mi = 0; mi < 4; ++mi)
#pragma unroll
            for (int r = 0; r < 4; ++r)
                e_part[mi][r] += __shfl_xor(e_part[mi][r], m);

    if (c == 0) {
#pragma unroll
        for (int mi = 0; mi < 4; ++mi)
#pragma unroll
            for (int r = 0; r < 4; ++r)
                red[wid][mi * 16 + g4 * 4 + r] = e_part[mi][r];
    }
    __syncthreads();
    if (tid < 64)
        e_out[row0 + tid] = red[0][tid] + red[1][tid] + red[2][tid] + red[3][tid];
}

// ---------------- kernel 4: masked softmax over T, in-place e->a ------------
__global__ void k_softmax(float* __restrict__ ea, const int* __restrict__ mask) {
    int b = blockIdx.x, tid = threadIdx.x;     // 1024 threads
    int lane = tid & 63, wid = tid >> 6;       // 16 waves
    __shared__ float red[16];
    float vals[4]; int ms[4];
    float mx = -1e30f;
#pragma unroll
    for (int j = 0; j < 4; ++j) {
        size_t t = (size_t)b * T_SZ + tid + j * 1024;
        vals[j] = ea[t];
        ms[j] = mask[t];
        if (ms[j]) mx = fmaxf(mx, vals[j]);
    }
#pragma unroll
    for (int m = 32; m >= 1; m >>= 1) mx = fmaxf(mx, __shfl_xor(mx, m));
    if (lane == 0) red[wid] = mx;
    __syncthreads();
    if (tid == 0) {
        float m2 = red[0];
        for (int i = 1; i < 16; ++i) m2 = fmaxf(m2, red[i]);
        red[0] = m2;
    }
    __syncthreads();
    mx = red[0];
    __syncthreads();
    float pv[4]; float sum = 0.f;
#pragma unroll
    for (int j = 0; j < 4; ++j) { pv[j] = ms[j] ? __expf(vals[j] - mx) : 0.f; sum += pv[j]; }
#pragma unroll
    for (int m = 32; m >= 1; m >>= 1) sum += __shfl_xor(sum, m);
    if (lane == 0) red[wid] = sum;
    __syncthreads();
    if (tid == 0) {
        float s2 = 0.f;
        for (int i = 0; i < 16; ++i) s2 += red[i];
        red[0] = s2;
    }
    __syncthreads();
    float inv = 1.f / red[0];
#pragma unroll
    for (int j = 0; j < 4; ++j) {
        size_t t = (size_t)b * T_SZ + tid + j * 1024;
        ea[t] = pv[j] * inv;
    }
}

// ---------------- kernel 5: ctx partials over T-chunks ----------------------
__global__ void k_ctx(const float* __restrict__ enc, const float* __restrict__ a,
                      float2* __restrict__ part) {
    int ts = blockIdx.x, b = blockIdx.y, tid = threadIdx.x;   // 32 x 32, 256 thr
    size_t rbase = (size_t)b * T_SZ + (size_t)ts * 128;
    const float2* ep = reinterpret_cast<const float2*>(enc + rbase * HID) + tid;
    const float* ap = a + rbase;
    float ax = 0.f, ay = 0.f, bx = 0.f, by = 0.f;
#pragma unroll 2
    for (int t = 0; t < 128; t += 2) {
        float a0 = ap[t], a1 = ap[t + 1];
        float2 e0 = ep[(size_t)t * 256], e1 = ep[(size_t)(t + 1) * 256];
        ax += a0 * e0.x; ay += a0 * e0.y;
        bx += a1 * e1.x; by += a1 * e1.y;
    }
    float2 r; r.x = ax + bx; r.y = ay + by;
    part[(size_t)(b * 32 + ts) * 256 + tid] = r;
}

// ---------------- kernel 6: reduce partials -> ctx --------------------------
__global__ void k_ctxred(const float* __restrict__ part, float* __restrict__ ctx) {
    int idx = blockIdx.x * 256 + threadIdx.x;   // 16384
    int b = idx >> 9, h = idx & 511;
    float sum = 0.f;
#pragma unroll
    for (int ts = 0; ts < 32; ++ts) sum += part[(size_t)(b * 32 + ts) * 512 + h];
    ctx[idx] = sum;
}

extern "C" void kernel_launch(void* const* d_in, const int* in_sizes, int n_in,
                              void* d_out, int out_size, void* d_ws, size_t ws_size,
                              hipStream_t stream) {
    const float* enc  = (const float*)d_in[0];   // [32,4096,512]
    const int*   mask = (const int*)d_in[1];     // [32,4096]
    const float* dec  = (const float*)d_in[2];   // [32,512]
    const float* Wh   = (const float*)d_in[3];   // [512,512]
    const float* Ws   = (const float*)d_in[4];   // [512,512]
    const float* v    = (const float*)d_in[5];   // [512]

    float* out = (float*)d_out;
    float* ctx = out;                // 16384 floats
    float* a   = out + 16384;        // 131072 floats (e then a, in place)

    // ws layout (floats): s[16384] | Wb (131072 f-slots) | part[524288]
    float* ws   = (float*)d_ws;
    float* s    = ws;
    uint4* Wb   = (uint4*)(ws + 16384);
    float* part = ws + 16384 + 131072;

    hipLaunchKernelGGL(k_s,      dim3(64),      dim3(256),  0, stream, dec, Ws, s);
    hipLaunchKernelGGL(k_pack,   dim3(128),     dim3(256),  0, stream, Wh, Wb);
    hipLaunchKernelGGL(k_gemm_e, dim3(2048),    dim3(256),  0, stream, enc, Wb, s, v, a);
    hipLaunchKernelGGL(k_softmax,dim3(32),      dim3(1024), 0, stream, a, mask);
    hipLaunchKernelGGL(k_ctx,    dim3(32, 32),  dim3(256),  0, stream, enc, a, (float2*)part);
    hipLaunchKernelGGL(k_ctxred, dim3(64),      dim3(256),  0, stream, part, ctx);
}

// Round 4
// 206.107 us; speedup vs baseline: 1.1683x; 1.1683x over previous
//
#include <hip/hip_runtime.h>
#include <hip/hip_bf16.h>
#include <cstdint>
#include <cstddef>

#define HID 512
#define T_SZ 4096

typedef __bf16 bf16x8 __attribute__((ext_vector_type(8)));
typedef float f32x4 __attribute__((ext_vector_type(4)));

__device__ __forceinline__ unsigned short f2bf_rne(float f) {
    unsigned int u = __float_as_uint(f);
    unsigned int r = (u + 0x7FFFu + ((u >> 16) & 1u)) >> 16;
    return (unsigned short)r;
}

__device__ __forceinline__ bf16x8 pack8(float4 x0, float4 x1) {
    bf16x8 r;
    r[0] = (__bf16)x0.x; r[1] = (__bf16)x0.y; r[2] = (__bf16)x0.z; r[3] = (__bf16)x0.w;
    r[4] = (__bf16)x1.x; r[5] = (__bf16)x1.y; r[6] = (__bf16)x1.z; r[7] = (__bf16)x1.w;
    return r;
}

__device__ __forceinline__ float fast_tanh(float x) {
    float e = __expf(2.0f * x);
    return 1.0f - 2.0f / (e + 1.0f);
}

__device__ __forceinline__ void gload_lds16(const void* g, void* l) {
    __builtin_amdgcn_global_load_lds(
        (const __attribute__((address_space(1))) unsigned int*)g,
        (__attribute__((address_space(3))) unsigned int*)l, 16, 0, 0);
}

// ---------------- kernel 1: s[b][n] = dot(dec[b,:], Ws[n,:]) ----------------
__global__ void k_s(const float* __restrict__ dec, const float* __restrict__ Ws,
                    float* __restrict__ s) {
    int idx = blockIdx.x * 256 + threadIdx.x;   // 16384 = 32*512
    int b = idx >> 9, n = idx & 511;
    const float4* dp = reinterpret_cast<const float4*>(dec + (size_t)b * HID);
    const float4* wp = reinterpret_cast<const float4*>(Ws + (size_t)n * HID);
    float acc = 0.f;
#pragma unroll 8
    for (int i = 0; i < HID / 4; ++i) {
        float4 d = dp[i], w = wp[i];
        acc += d.x * w.x + d.y * w.y + d.z * w.z + d.w * w.w;
    }
    s[idx] = acc;
}

// ------------- kernel 2: pack W_h -> bf16 fragments (kk-major) --------------
// Chunk index = kk*2048 + n4*64 + (g*16 + c); chunk (uint4) holds
// W[n4*16 + c][kk*32 + g*8 + j], j=0..7 as bf16.
__global__ void k_pack(const float* __restrict__ Wh, uint4* __restrict__ Wb) {
    int idx = blockIdx.x * 256 + threadIdx.x;   // 32768, 8 elems each
    int n = idx >> 6;
    int k0 = (idx & 63) * 8;
    const float4* p = reinterpret_cast<const float4*>(Wh + (size_t)n * HID + k0);
    float4 x0 = p[0], x1 = p[1];
    uint4 w;
    w.x = f2bf_rne(x0.x) | ((unsigned)f2bf_rne(x0.y) << 16);
    w.y = f2bf_rne(x0.z) | ((unsigned)f2bf_rne(x0.w) << 16);
    w.z = f2bf_rne(x1.x) | ((unsigned)f2bf_rne(x1.y) << 16);
    w.w = f2bf_rne(x1.z) | ((unsigned)f2bf_rne(x1.w) << 16);
    int n4 = n >> 4, c = n & 15, kk = k0 >> 5, g = (k0 >> 3) & 3;
    Wb[(size_t)kk * 2048 + n4 * 64 + g * 16 + c] = w;
}

// ------------- kernel 3: fused h = enc@Wh^T ; e_part = sum tanh(h+s).v ------
// BM=128, BN=256 (h-half of N), BK=32. 4 waves (2M x 2N), each 64x128.
// Tri-buffered LDS, staging issued 2 K-steps ahead, counted vmcnt(8) at the
// per-step barrier (loads stay in flight across barriers). 2 blocks/CU.
__global__ void __launch_bounds__(256, 2) k_gemm_e(
    const float* __restrict__ enc, const uint4* __restrict__ Wb,
    const float* __restrict__ s, const float* __restrict__ v,
    float* __restrict__ part_e) {
    __shared__ __align__(16) unsigned char Abuf[3][8192];    // 512 chunks x 16B
    __shared__ __align__(16) unsigned char Bbuf[3][16384];   // 1024 chunks x 16B
    __shared__ float red[4][64];

    const int tid = threadIdx.x;
    // bijective XCD swizzle: 2048 blocks, 8 XCDs, 256/XCD; h-pairs adjacent.
    const int p = blockIdx.x;
    const int logical = (p & 7) * 256 + (p >> 3);
    const int h = logical & 1;
    const int m = logical >> 1;                 // 0..1023
    const size_t row0 = (size_t)m * 128;
    const int b = (int)(row0 >> 12);

    const int lane = tid & 63, wid = tid >> 6;
    const int c = lane & 15, g4 = lane >> 4;
    const int wm = wid >> 1, wn = wid & 1;

    // epilogue constants
    float sv_s[8], sv_v[8];
#pragma unroll
    for (int ni = 0; ni < 8; ++ni) {
        int n = h * 256 + wn * 128 + ni * 16 + c;
        sv_s[ni] = s[b * HID + n];
        sv_v[ni] = v[n];
    }
    // drain sv loads so loop vmcnt counting is exact
    asm volatile("s_waitcnt vmcnt(0)" ::: "memory");

    // A staging geometry: thread owns chunks tid and tid+256 of each step.
    // chunk ch: rt=ch>>6, g=(ch>>4)&3, cc=ch&15 -> row=rt*16+cc, k0=g*8
    const int rt0 = tid >> 6, gg = (tid >> 4) & 3, cc = tid & 15;
    const float* Ag0 = enc + (row0 + rt0 * 16 + cc) * HID + gg * 8;
    const float* Ag1 = Ag0 + (size_t)64 * HID;
    // B source: this lane's fragment stream
    const uint4* Bg = Wb + h * 1024 + wid * 64 + lane;   // + kk*2048 + i*256

    float4 ar[2][4];   // 2-deep A-register staging (static-indexed after unroll)

    // ---- prologue: stage steps 0 and 1 ----
#pragma unroll
    for (int q = 0; q < 2; ++q)
        ar[0][q * 2]     = *reinterpret_cast<const float4*>((q ? Ag1 : Ag0)),
        ar[0][q * 2 + 1] = *reinterpret_cast<const float4*>((q ? Ag1 : Ag0) + 4);
#pragma unroll
    for (int i = 0; i < 4; ++i)
        gload_lds16(Bg + i * 256, &Bbuf[0][(i * 256 + wid * 64) * 16]);
    asm volatile("" ::: "memory");   // keep stage(0) older than stage(1)
#pragma unroll
    for (int q = 0; q < 2; ++q)
        ar[1][q * 2]     = *reinterpret_cast<const float4*>((q ? Ag1 : Ag0) + 32),
        ar[1][q * 2 + 1] = *reinterpret_cast<const float4*>((q ? Ag1 : Ag0) + 36);
#pragma unroll
    for (int i = 0; i < 4; ++i)
        gload_lds16(Bg + 2048 + i * 256, &Bbuf[1][(i * 256 + wid * 64) * 16]);
    // write A(0) (compiler inserts the right vmcnt for ar[0])
    *reinterpret_cast<bf16x8*>(&Abuf[0][tid * 16])         = pack8(ar[0][0], ar[0][1]);
    *reinterpret_cast<bf16x8*>(&Abuf[0][(tid + 256) * 16]) = pack8(ar[0][2], ar[0][3]);
    // B(0) must be done; A(1),B(1) (8 ops) stay in flight
    asm volatile("s_waitcnt vmcnt(8) lgkmcnt(0)\n\ts_barrier" ::: "memory");

    f32x4 acc[4][8] = {};   // [mi][ni]

#pragma unroll
    for (int kk = 0; kk < 16; ++kk) {
        // ---- stage kk+2 (A->regs, B->LDS) ----
        if (kk + 2 <= 15) {
#pragma unroll
            for (int q = 0; q < 2; ++q) {
                const float* Agq = (q ? Ag1 : Ag0) + (kk + 2) * 32;
                ar[kk & 1][q * 2]     = *reinterpret_cast<const float4*>(Agq);
                ar[kk & 1][q * 2 + 1] = *reinterpret_cast<const float4*>(Agq + 4);
            }
#pragma unroll
            for (int i = 0; i < 4; ++i)
                gload_lds16(Bg + (size_t)(kk + 2) * 2048 + i * 256,
                            &Bbuf[(kk + 2) % 3][(i * 256 + wid * 64) * 16]);
        }
        // ---- write A(kk+1) from regs loaded last iteration ----
        if (kk + 1 <= 15) {
            const int wb = (kk + 1) % 3, wp_ = (kk + 1) & 1;
            *reinterpret_cast<bf16x8*>(&Abuf[wb][tid * 16])         = pack8(ar[wp_][0], ar[wp_][1]);
            *reinterpret_cast<bf16x8*>(&Abuf[wb][(tid + 256) * 16]) = pack8(ar[wp_][2], ar[wp_][3]);
        }
        // ---- compute step kk ----
        bf16x8 af[4], bfr[8];
#pragma unroll
        for (int mi = 0; mi < 4; ++mi)
            af[mi] = *reinterpret_cast<const bf16x8*>(
                &Abuf[kk % 3][((wm * 4 + mi) * 64 + lane) * 16]);
#pragma unroll
        for (int ni = 0; ni < 8; ++ni)
            bfr[ni] = *reinterpret_cast<const bf16x8*>(
                &Bbuf[kk % 3][((wn * 8 + ni) * 64 + lane) * 16]);
#pragma unroll
        for (int mi = 0; mi < 4; ++mi)
#pragma unroll
            for (int ni = 0; ni < 8; ++ni)
                acc[mi][ni] = __builtin_amdgcn_mfma_f32_16x16x32_bf16(
                    af[mi], bfr[ni], acc[mi][ni], 0, 0, 0);
        // ---- barrier with counted vmcnt: keep this iter's 8 staging ops in flight
        if (kk <= 13)
            asm volatile("s_waitcnt vmcnt(8) lgkmcnt(0)\n\ts_barrier" ::: "memory");
        else if (kk == 14)
            asm volatile("s_waitcnt vmcnt(0) lgkmcnt(0)\n\ts_barrier" ::: "memory");
    }

    // ---- epilogue: e_part[row] += tanh(h + s[n]) * v[n] over this half ----
    float e_part[4][4] = {};   // [mi][r]
#pragma unroll
    for (int ni = 0; ni < 8; ++ni) {
        float sn = sv_s[ni], vn = sv_v[ni];
#pragma unroll
        for (int mi = 0; mi < 4; ++mi)
#pragma unroll
            for (int r = 0; r < 4; ++r)
                e_part[mi][r] += fast_tanh(acc[mi][ni][r] + sn) * vn;
    }
    // reduce across the 16 n-residue lanes (bits 0..3)
#pragma unroll
    for (int mm = 1; mm <= 8; mm <<= 1)
#pragma unroll
        for (int mi = 0; mi < 4; ++mi)
#pragma unroll
            for (int r = 0; r < 4; ++r)
                e_part[mi][r] += __shfl_xor(e_part[mi][r], mm);

    if (c == 0) {
#pragma unroll
        for (int mi = 0; mi < 4; ++mi)
#pragma unroll
            for (int r = 0; r < 4; ++r)
                red[wid][mi * 16 + g4 * 4 + r] = e_part[mi][r];
    }
    __syncthreads();
    if (tid < 128) {
        int wm2 = tid >> 6, r = tid & 63;
        part_e[(size_t)h * 131072 + row0 + tid] =
            red[wm2 * 2][r] + red[wm2 * 2 + 1][r];
    }
}

// ---------------- kernel 4: e = part0+part1; masked softmax -> a ------------
__global__ void k_softmax(const float* __restrict__ part_e, float* __restrict__ a,
                          const int* __restrict__ mask) {
    int b = blockIdx.x, tid = threadIdx.x;     // 1024 threads
    int lane = tid & 63, wid = tid >> 6;       // 16 waves
    __shared__ float red[16];
    float vals[4]; int ms[4];
    float mx = -1e30f;
#pragma unroll
    for (int j = 0; j < 4; ++j) {
        size_t t = (size_t)b * T_SZ + tid + j * 1024;
        vals[j] = part_e[t] + part_e[131072 + t];
        ms[j] = mask[t];
        if (ms[j]) mx = fmaxf(mx, vals[j]);
    }
#pragma unroll
    for (int m = 32; m >= 1; m >>= 1) mx = fmaxf(mx, __shfl_xor(mx, m));
    if (lane == 0) red[wid] = mx;
    __syncthreads();
    if (tid == 0) {
        float m2 = red[0];
        for (int i = 1; i < 16; ++i) m2 = fmaxf(m2, red[i]);
        red[0] = m2;
    }
    __syncthreads();
    mx = red[0];
    __syncthreads();
    float pv[4]; float sum = 0.f;
#pragma unroll
    for (int j = 0; j < 4; ++j) { pv[j] = ms[j] ? __expf(vals[j] - mx) : 0.f; sum += pv[j]; }
#pragma unroll
    for (int m = 32; m >= 1; m >>= 1) sum += __shfl_xor(sum, m);
    if (lane == 0) red[wid] = sum;
    __syncthreads();
    if (tid == 0) {
        float s2 = 0.f;
        for (int i = 0; i < 16; ++i) s2 += red[i];
        red[0] = s2;
    }
    __syncthreads();
    float inv = 1.f / red[0];
#pragma unroll
    for (int j = 0; j < 4; ++j)
        a[(size_t)b * T_SZ + tid + j * 1024] = pv[j] * inv;
}

// ---------------- kernel 5: ctx partials over T-chunks ----------------------
__global__ void k_ctx(const float* __restrict__ enc, const float* __restrict__ a,
                      float2* __restrict__ part) {
    int ts = blockIdx.x, b = blockIdx.y, tid = threadIdx.x;   // 32 x 32, 256 thr
    size_t rbase = (size_t)b * T_SZ + (size_t)ts * 128;
    const float2* ep = reinterpret_cast<const float2*>(enc + rbase * HID) + tid;
    const float* ap = a + rbase;
    float ax = 0.f, ay = 0.f, bx = 0.f, by = 0.f;
#pragma unroll 2
    for (int t = 0; t < 128; t += 2) {
        float a0 = ap[t], a1 = ap[t + 1];
        float2 e0 = ep[(size_t)t * 256], e1 = ep[(size_t)(t + 1) * 256];
        ax += a0 * e0.x; ay += a0 * e0.y;
        bx += a1 * e1.x; by += a1 * e1.y;
    }
    float2 r; r.x = ax + bx; r.y = ay + by;
    part[(size_t)(b * 32 + ts) * 256 + tid] = r;
}

// ---------------- kernel 6: reduce partials -> ctx --------------------------
__global__ void k_ctxred(const float* __restrict__ part, float* __restrict__ ctx) {
    int idx = blockIdx.x * 256 + threadIdx.x;   // 16384
    int b = idx >> 9, h = idx & 511;
    float sum = 0.f;
#pragma unroll
    for (int ts = 0; ts < 32; ++ts) sum += part[(size_t)(b * 32 + ts) * 512 + h];
    ctx[idx] = sum;
}

extern "C" void kernel_launch(void* const* d_in, const int* in_sizes, int n_in,
                              void* d_out, int out_size, void* d_ws, size_t ws_size,
                              hipStream_t stream) {
    const float* enc  = (const float*)d_in[0];   // [32,4096,512]
    const int*   mask = (const int*)d_in[1];     // [32,4096]
    const float* dec  = (const float*)d_in[2];   // [32,512]
    const float* Wh   = (const float*)d_in[3];   // [512,512]
    const float* Ws   = (const float*)d_in[4];   // [512,512]
    const float* v    = (const float*)d_in[5];   // [512]

    float* out = (float*)d_out;
    float* ctx = out;                // 16384 floats
    float* a   = out + 16384;        // 131072 floats

    // ws layout (floats): s[16384] | Wb (131072 f-slots) | part_e[262144] | part[524288]
    float* ws     = (float*)d_ws;
    float* s      = ws;
    uint4* Wb     = (uint4*)(ws + 16384);
    float* part_e = ws + 16384 + 131072;
    float* part   = part_e + 262144;

    hipLaunchKernelGGL(k_s,      dim3(64),      dim3(256),  0, stream, dec, Ws, s);
    hipLaunchKernelGGL(k_pack,   dim3(128),     dim3(256),  0, stream, Wh, Wb);
    hipLaunchKernelGGL(k_gemm_e, dim3(2048),    dim3(256),  0, stream, enc, Wb, s, v, part_e);
    hipLaunchKernelGGL(k_softmax,dim3(32),      dim3(1024), 0, stream, part_e, a, mask);
    hipLaunchKernelGGL(k_ctx,    dim3(32, 32),  dim3(256),  0, stream, enc, a, (float2*)part);
    hipLaunchKernelGGL(k_ctxred, dim3(64),      dim3(256),  0, stream, part, ctx);
}